// Round 7
// baseline (269.086 us; speedup 1.0000x reference)
//
#include <hip/hip_runtime.h>
#include <math.h>

#define B_    4096
#define N_    10
#define DIN_  32
#define D_    128
#define PHI_  256
#define RHO_  128
#define L_    3
#define EPS_  1e-5f

// ---- bf16 helpers (bits in short) ----
__device__ __forceinline__ short f2bs(float f) {            // f32 -> bf16 RNE
    unsigned u = __float_as_uint(f);
    u += 0x7fffu + ((u >> 16) & 1u);
    return (short)(u >> 16);
}
__device__ __forceinline__ float bs2f(short s) {
    return __uint_as_float(((unsigned)(unsigned short)s) << 16);
}

typedef short bf16x8 __attribute__((ext_vector_type(8)));
typedef float f32x4  __attribute__((ext_vector_type(4)));
typedef float v2f    __attribute__((ext_vector_type(2)));

__device__ __forceinline__ v2f splat2(float s) { v2f r; r.x = s; r.y = s; return r; }
__device__ __forceinline__ v2f fma2(v2f a, v2f b, v2f c) { return __builtin_elementwise_fma(a, b, c); }

// ---- d_ws layout (bf16 elements). Fragment unit = 64 lanes x 8 el = 512 el.
// For matrix W[K][N]: frag (nt,ks) at ((nt*KS+ks)*64+lane)*8, lane holds
// W[ks*32+(lane>>4)*8+j][nt*16+(lane&15)], j=0..7  (B-operand layout, 16x16x32)
#define WS_WE1 0
#define WS_WE2 4096
#define WS_RGW 20480
#define WS_RGR 118784
#define WS_L1  167936
#define WS_L2  217088
#define WS_P1  266240
#define WS_P2  299008
#define WS_R1  364544

// ================= prep kernel: fp32 weights -> bf16 B-fragments ==========
__global__ __launch_bounds__(64)
void prep_weights(const float* __restrict__ We1, const float* __restrict__ We2,
                  const float* __restrict__ rgw, const float* __restrict__ rgr,
                  const float* __restrict__ l1w, const float* __restrict__ l2w,
                  const float* __restrict__ p1w, const float* __restrict__ p2w,
                  const float* __restrict__ r1w, short* __restrict__ ws)
{
    int bi = blockIdx.x, l = threadIdx.x;
    const float* src; int KS, Nw, dstOff, tt;
    if      (bi <   8) { src = We1; KS = 1; Nw = 128; dstOff = WS_WE1; tt = bi; }
    else if (bi <  40) { src = We2; KS = 4; Nw = 128; dstOff = WS_WE2; tt = bi - 8; }
    else if (bi < 232) { int m = (bi - 40) >> 5;  src = rgw + m * 16384; KS = 4; Nw = 128; dstOff = WS_RGW + m * 16384; tt = (bi - 40)  & 31; }
    else if (bi < 328) { int m = (bi - 232) >> 5; src = rgr + m * 16384; KS = 4; Nw = 128; dstOff = WS_RGR + m * 16384; tt = (bi - 232) & 31; }
    else if (bi < 424) { int m = (bi - 328) >> 5; src = l1w + m * 16384; KS = 4; Nw = 128; dstOff = WS_L1  + m * 16384; tt = (bi - 328) & 31; }
    else if (bi < 520) { int m = (bi - 424) >> 5; src = l2w + m * 16384; KS = 4; Nw = 128; dstOff = WS_L2  + m * 16384; tt = (bi - 424) & 31; }
    else if (bi < 584) { src = p1w; KS = 4; Nw = 256; dstOff = WS_P1; tt = bi - 520; }
    else if (bi < 712) { src = p2w; KS = 8; Nw = 256; dstOff = WS_P2; tt = bi - 584; }
    else               { src = r1w; KS = 8; Nw = 128; dstOff = WS_R1; tt = bi - 712; }
    int nt = tt / KS, ks = tt - nt * KS;
    int kbase = ks * 32 + (l >> 4) * 8;
    int col   = nt * 16 + (l & 15);
    union { short s[8]; int4 v; } u;
#pragma unroll
    for (int j = 0; j < 8; ++j)
        u.s[j] = f2bs(src[(size_t)(kbase + j) * Nw + col]);
    *(int4*)(ws + dstOff + ((size_t)tt * 64 + l) * 8) = u.v;
}

// ================= main kernel: 1 wave = 2 graphs ==========================
// A-operand layout: lane holds A[m=lane&15][k=(lane>>4)*8+j]; rows >=10 clamped to 9
// C/D layout: col = lane&15, row = (lane>>4)*4 + reg
// B-fragments loaded ONCE per ks-step and applied to both graphs (halves L2 traffic).

template<int NT>
__device__ __forceinline__ void initC(f32x4* acc, const float* __restrict__ bias, int c16) {
#pragma unroll
    for (int nt = 0; nt < NT; ++nt) {
        float bv = bias[nt * 16 + c16];
        acc[nt] = (f32x4){bv, bv, bv, bv};
    }
}

// dual-graph, software-pipelined, A from LDS bf16
template<int KS>
__device__ __forceinline__ void mm8p2_a16(const short* __restrict__ Wf,
                                          const short* __restrict__ A0,
                                          const short* __restrict__ A1, int ldA,
                                          int mrow, int q, int l,
                                          f32x4* acc0, f32x4* acc1)
{
    const short* ap0 = A0 + mrow * ldA + q * 8;
    const short* ap1 = A1 + mrow * ldA + q * 8;
    const short* wp  = Wf + l * 8;
    bf16x8 a0 = *(const bf16x8*)ap0;
    bf16x8 a1 = *(const bf16x8*)ap1;
    bf16x8 bcur[8], bnxt[8];
#pragma unroll
    for (int nt = 0; nt < 8; ++nt) bcur[nt] = *(const bf16x8*)(wp + (size_t)nt * KS * 512);
#pragma unroll
    for (int ks = 0; ks < KS; ++ks) {
        bf16x8 a0n = a0, a1n = a1;
#pragma unroll
        for (int nt = 0; nt < 8; ++nt) bnxt[nt] = bcur[nt];
        if (ks + 1 < KS) {
            a0n = *(const bf16x8*)(ap0 + (ks + 1) * 32);
            a1n = *(const bf16x8*)(ap1 + (ks + 1) * 32);
#pragma unroll
            for (int nt = 0; nt < 8; ++nt)
                bnxt[nt] = *(const bf16x8*)(wp + (size_t)(nt * KS + ks + 1) * 512);
        }
#pragma unroll
        for (int nt = 0; nt < 8; ++nt)
            acc0[nt] = __builtin_amdgcn_mfma_f32_16x16x32_bf16(a0, bcur[nt], acc0[nt], 0, 0, 0);
#pragma unroll
        for (int nt = 0; nt < 8; ++nt)
            acc1[nt] = __builtin_amdgcn_mfma_f32_16x16x32_bf16(a1, bcur[nt], acc1[nt], 0, 0, 0);
        a0 = a0n; a1 = a1n;
#pragma unroll
        for (int nt = 0; nt < 8; ++nt) bcur[nt] = bnxt[nt];
    }
}

// dual-graph, software-pipelined, A from LDS fp32 (converted on the fly)
template<int KS>
__device__ __forceinline__ void mm8p2_a32(const short* __restrict__ Wf,
                                          const float* __restrict__ A0,
                                          const float* __restrict__ A1, int ldA,
                                          int mrow, int q, int l,
                                          f32x4* acc0, f32x4* acc1)
{
    const float* ap0 = A0 + mrow * ldA + q * 8;
    const float* ap1 = A1 + mrow * ldA + q * 8;
    const short* wp  = Wf + l * 8;
    auto cvt = [](const float* p) {
        f32x4 x0 = *(const f32x4*)p;
        f32x4 x1 = *(const f32x4*)(p + 4);
        bf16x8 a;
        a[0] = f2bs(x0[0]); a[1] = f2bs(x0[1]); a[2] = f2bs(x0[2]); a[3] = f2bs(x0[3]);
        a[4] = f2bs(x1[0]); a[5] = f2bs(x1[1]); a[6] = f2bs(x1[2]); a[7] = f2bs(x1[3]);
        return a;
    };
    bf16x8 a0 = cvt(ap0);
    bf16x8 a1 = cvt(ap1);
    bf16x8 bcur[8], bnxt[8];
#pragma unroll
    for (int nt = 0; nt < 8; ++nt) bcur[nt] = *(const bf16x8*)(wp + (size_t)nt * KS * 512);
#pragma unroll
    for (int ks = 0; ks < KS; ++ks) {
        bf16x8 a0n = a0, a1n = a1;
#pragma unroll
        for (int nt = 0; nt < 8; ++nt) bnxt[nt] = bcur[nt];
        if (ks + 1 < KS) {
            a0n = cvt(ap0 + (ks + 1) * 32);
            a1n = cvt(ap1 + (ks + 1) * 32);
#pragma unroll
            for (int nt = 0; nt < 8; ++nt)
                bnxt[nt] = *(const bf16x8*)(wp + (size_t)(nt * KS + ks + 1) * 512);
        }
#pragma unroll
        for (int nt = 0; nt < 8; ++nt)
            acc0[nt] = __builtin_amdgcn_mfma_f32_16x16x32_bf16(a0, bcur[nt], acc0[nt], 0, 0, 0);
#pragma unroll
        for (int nt = 0; nt < 8; ++nt)
            acc1[nt] = __builtin_amdgcn_mfma_f32_16x16x32_bf16(a1, bcur[nt], acc1[nt], 0, 0, 0);
        a0 = a0n; a1 = a1n;
#pragma unroll
        for (int nt = 0; nt < 8; ++nt) bcur[nt] = bnxt[nt];
    }
}

// store C tiles as bf16 into LDS (row-major, ldD elements), rows >= 10 dropped
template<int NT, bool RELU>
__device__ __forceinline__ void storeC16(const f32x4* acc, short* __restrict__ dst,
                                         int ldD, int q, int c16) {
#pragma unroll
    for (int nt = 0; nt < NT; ++nt) {
#pragma unroll
        for (int i = 0; i < 4; ++i) {
            int r = q * 4 + i;
            if (r < 10) {
                float v = acc[nt][i];
                if (RELU) v = fmaxf(v, 0.f);
                dst[r * ldD + nt * 16 + c16] = f2bs(v);
            }
        }
    }
}

#define HLD  132   // Hf row stride (f32), 528 B — 4-bank row stagger
#define GLD  264   // Gb row stride (bf16), 528 B — slots S0=+0, S1=+136
#define H2LD 136   // H2 row stride (bf16), 272 B — 4-bank row stagger

__global__ __launch_bounds__(64, 2)
void gcn_main(const float* __restrict__ A, const float* __restrict__ X,
              const int* __restrict__ home_mask,
              const float* __restrict__ be1, const float* __restrict__ be2,
              const float* __restrict__ rgcn_b,
              const float* __restrict__ l1b, const float* __restrict__ l2b,
              const float* __restrict__ ln_g, const float* __restrict__ ln_b,
              const float* __restrict__ p1b, const float* __restrict__ p2b,
              const float* __restrict__ r1b, const float* __restrict__ r2w,
              const short* __restrict__ ws, float* __restrict__ out)
{
    const int b0  = blockIdx.x * 2;     // graphs b0, b0+1
    const int l   = threadIdx.x;        // 0..63
    const int q   = l >> 4;
    const int c16 = l & 15;
    const int mrow = (c16 < 10) ? c16 : 9;    // A-row clamp (C rows>=10 ignored)

    // Buffer flow invariant: every phase's write-buffer is disjoint from its
    // read-buffers (no in-place phases).
    __shared__ __align__(16) float HfS[2][N_ * HLD];
    __shared__ __align__(16) short GbS[2][N_ * GLD];
    __shared__ __align__(16) short H2S[2][N_ * H2LD];   // H2 out; later RhoS overlay
    __shared__ float AabsS[2][100], M1S[2][100];
    __shared__ float invc0S[2][N_], invc1S[2][N_];
    __shared__ float hmfS[2][16], awfS[2][16];

    // ---- stage A, home_mask ----
    {
#pragma unroll
        for (int e = l; e < 200; e += 64) {
            int g = (e >= 100) ? 1 : 0;
            int e2 = e - g * 100;
            float a = A[(size_t)(b0 + g) * 100 + e2];
            AabsS[g][e2] = fabsf(a);
            M1S[g][e2]  = (a > 0.f) ? 1.f : 0.f;
        }
        if (l < 16) {
#pragma unroll
            for (int g = 0; g < 2; ++g) {
                float hm = 0.f, aw = 0.f;
                if (l < 10) { hm = (float)home_mask[(b0 + g) * N_ + l]; aw = 1.f - hm; }
                hmfS[g][l] = hm; awfS[g][l] = aw;
            }
        }
        if (l < 10) {
#pragma unroll
            for (int g = 0; g < 2; ++g) {
                float c1 = 0.f;
#pragma unroll
                for (int i = 0; i < 10; ++i) c1 += M1S[g][i * 10 + l];
                invc1S[g][l] = 1.f / fmaxf(c1, 1.f);
                invc0S[g][l] = 1.f / fmaxf(10.f - c1, 1.f);
            }
        }
    }

    // ---- embed1: H1 = relu(X@We1 + be1) -> S0[g] ----
    {
        f32x4 acc0[8], acc1[8];
        initC<8>(acc0, be1, c16);
        initC<8>(acc1, be1, c16);
        auto cvtX = [&](int g) {
            const float* xg = X + (size_t)(b0 + g) * (N_ * DIN_) + mrow * DIN_ + q * 8;
            f32x4 x0 = *(const f32x4*)xg;
            f32x4 x1 = *(const f32x4*)(xg + 4);
            bf16x8 a;
            a[0] = f2bs(x0[0]); a[1] = f2bs(x0[1]); a[2] = f2bs(x0[2]); a[3] = f2bs(x0[3]);
            a[4] = f2bs(x1[0]); a[5] = f2bs(x1[1]); a[6] = f2bs(x1[2]); a[7] = f2bs(x1[3]);
            return a;
        };
        bf16x8 a0 = cvtX(0), a1 = cvtX(1);
#pragma unroll
        for (int nt = 0; nt < 8; ++nt) {
            bf16x8 bv = *(const bf16x8*)(ws + WS_WE1 + ((size_t)nt * 64 + l) * 8);
            acc0[nt] = __builtin_amdgcn_mfma_f32_16x16x32_bf16(a0, bv, acc0[nt], 0, 0, 0);
            acc1[nt] = __builtin_amdgcn_mfma_f32_16x16x32_bf16(a1, bv, acc1[nt], 0, 0, 0);
        }
        storeC16<8, true>(acc0, &GbS[0][0], GLD, q, c16);
        storeC16<8, true>(acc1, &GbS[1][0], GLD, q, c16);
    }
    // ---- embed2: H = H1@We2 + be2 -> Hf[g] (fp32) ----
    {
        f32x4 acc0[8], acc1[8];
        initC<8>(acc0, be2, c16);
        initC<8>(acc1, be2, c16);
        mm8p2_a16<4>(ws + WS_WE2, &GbS[0][0], &GbS[1][0], GLD, mrow, q, l, acc0, acc1);
#pragma unroll
        for (int nt = 0; nt < 8; ++nt)
#pragma unroll
            for (int i = 0; i < 4; ++i) {
                int r = q * 4 + i;
                if (r < 10) {
                    HfS[0][r * HLD + nt * 16 + c16] = acc0[nt][i];
                    HfS[1][r * HLD + nt * 16 + c16] = acc1[nt][i];
                }
            }
    }

    const v2f lg2 = *(const v2f*)(ln_g + 2 * l);
    const v2f lb2 = *(const v2f*)(ln_b + 2 * l);

    // ---- layers ----
    for (int ll = 0; ll < L_; ++ll) {
        // means [reads HfS; writes S0=mean0, S1=mean1]
#pragma unroll
        for (int g = 0; g < 2; ++g) {
            v2f hv[N_];
#pragma unroll
            for (int i = 0; i < N_; ++i) hv[i] = *(const v2f*)(&HfS[g][i * HLD] + 2 * l);
            v2f st = hv[0];
#pragma unroll
            for (int i = 1; i < N_; ++i) st += hv[i];
#pragma unroll
            for (int j = 0; j < N_; ++j) {
                v2f s1 = splat2(0.f);
#pragma unroll
                for (int i = 0; i < N_; ++i) s1 = fma2(splat2(M1S[g][i * 10 + j]), hv[i], s1);
                v2f m0 = (st - s1) * splat2(invc0S[g][j]);
                v2f m1 = s1 * splat2(invc1S[g][j]);
                short2 w0; w0.x = f2bs(m0.x); w0.y = f2bs(m0.y);
                short2 w1; w1.x = f2bs(m1.x); w1.y = f2bs(m1.y);
                *(short2*)(&GbS[g][j * GLD]       + 2 * l) = w0;
                *(short2*)(&GbS[g][j * GLD + 136] + 2 * l) = w1;
            }
        }
        // H2 = mean0@W0 + mean1@W1 + H@root + b [reads S0,S1,HfS; writes H2S]
        {
            f32x4 acc0[8], acc1[8];
            initC<8>(acc0, rgcn_b + ll * D_, c16);
            initC<8>(acc1, rgcn_b + ll * D_, c16);
            mm8p2_a16<4>(ws + WS_RGW + (size_t)(ll * 2 + 0) * 16384,
                         &GbS[0][0],   &GbS[1][0],   GLD, mrow, q, l, acc0, acc1);
            mm8p2_a16<4>(ws + WS_RGW + (size_t)(ll * 2 + 1) * 16384,
                         &GbS[0][136], &GbS[1][136], GLD, mrow, q, l, acc0, acc1);
            mm8p2_a32<4>(ws + WS_RGR + (size_t)ll * 16384,
                         &HfS[0][0], &HfS[1][0], HLD, mrow, q, l, acc0, acc1);
            storeC16<8, false>(acc0, &H2S[0][0], H2LD, q, c16);
            storeC16<8, false>(acc1, &H2S[1][0], H2LD, q, c16);
        }
        // agg + LayerNorm + relu [reads H2S; writes S0]
#pragma unroll
        for (int g = 0; g < 2; ++g) {
            v2f ag[N_];
#pragma unroll
            for (int i = 0; i < N_; ++i) ag[i] = splat2(0.f);
#pragma unroll
            for (int j = 0; j < N_; ++j) {
                short2 hh = *(const short2*)(&H2S[g][j * H2LD] + 2 * l);
                v2f h2; h2.x = bs2f(hh.x); h2.y = bs2f(hh.y);
#pragma unroll
                for (int i = 0; i < N_; ++i)
                    ag[i] = fma2(splat2(AabsS[g][i * 10 + j]), h2, ag[i]);
            }
#pragma unroll
            for (int i = 0; i < N_; ++i) {
                float s  = ag[i].x + ag[i].y;
                float ss = fmaf(ag[i].x, ag[i].x, ag[i].y * ag[i].y);
#pragma unroll
                for (int off = 32; off > 0; off >>= 1) {
                    s  += __shfl_xor(s,  off);
                    ss += __shfl_xor(ss, off);
                }
                float mu   = s * (1.f / 128.f);
                float var  = ss * (1.f / 128.f) - mu * mu;
                float rstd = rsqrtf(var + EPS_);
                v2f v = fma2((ag[i] - splat2(mu)) * splat2(rstd), lg2, lb2);
                short2 wv; wv.x = f2bs(fmaxf(v.x, 0.f)); wv.y = f2bs(fmaxf(v.y, 0.f));
                *(short2*)(&GbS[g][i * GLD] + 2 * l) = wv;
            }
        }
        // MLP1: relu(LNout @ l1w + l1b) [reads S0; writes S1]
        {
            f32x4 acc0[8], acc1[8];
            initC<8>(acc0, l1b + ll * D_, c16);
            initC<8>(acc1, l1b + ll * D_, c16);
            mm8p2_a16<4>(ws + WS_L1 + (size_t)ll * 16384,
                         &GbS[0][0], &GbS[1][0], GLD, mrow, q, l, acc0, acc1);
            storeC16<8, true>(acc0, &GbS[0][136], GLD, q, c16);
            storeC16<8, true>(acc1, &GbS[1][136], GLD, q, c16);
        }
        // MLP2: hidden @ l2w + l2b [reads S1; accumulates into HfS]
        {
            f32x4 acc0[8], acc1[8];
            initC<8>(acc0, l2b + ll * D_, c16);
            initC<8>(acc1, l2b + ll * D_, c16);
            mm8p2_a16<4>(ws + WS_L2 + (size_t)ll * 16384,
                         &GbS[0][136], &GbS[1][136], GLD, mrow, q, l, acc0, acc1);
#pragma unroll
            for (int nt = 0; nt < 8; ++nt)
#pragma unroll
                for (int i = 0; i < 4; ++i) {
                    int r = q * 4 + i;
                    if (r < 10) {
                        HfS[0][r * HLD + nt * 16 + c16] += acc0[nt][i];
                        HfS[1][r * HLD + nt * 16 + c16] += acc1[nt][i];
                    }
                }
        }
    }

    // ---- phi1: relu(H @ p1w + p1b) [reads HfS; writes GbS cols 0..255] ----
    {
        f32x4 acc0[8], acc1[8];
        initC<8>(acc0, p1b, c16);
        initC<8>(acc1, p1b, c16);
        mm8p2_a32<4>(ws + WS_P1, &HfS[0][0], &HfS[1][0], HLD, mrow, q, l, acc0, acc1);
        storeC16<8, true>(acc0, &GbS[0][0], GLD, q, c16);
        storeC16<8, true>(acc1, &GbS[1][0], GLD, q, c16);
        initC<8>(acc0, p1b + 128, c16);
        initC<8>(acc1, p1b + 128, c16);
        mm8p2_a32<4>(ws + WS_P1 + 8 * 4 * 512, &HfS[0][0], &HfS[1][0], HLD, mrow, q, l, acc0, acc1);
        storeC16<8, true>(acc0, &GbS[0][128], GLD, q, c16);
        storeC16<8, true>(acc1, &GbS[1][128], GLD, q, c16);
    }
    // ---- phi2 + masked column sums [reads GbS; writes RhoS(=H2S)] ----
    {
#pragma unroll
        for (int half = 0; half < 2; ++half) {
            f32x4 acc0[8], acc1[8];
            initC<8>(acc0, p2b + half * 128, c16);
            initC<8>(acc1, p2b + half * 128, c16);
            mm8p2_a16<8>(ws + WS_P2 + (size_t)half * 8 * 8 * 512,
                         &GbS[0][0], &GbS[1][0], GLD, mrow, q, l, acc0, acc1);
#pragma unroll
            for (int g = 0; g < 2; ++g) {
                const f32x4* acc = (g == 0) ? acc0 : acc1;
                float hm0 = hmfS[g][q * 4 + 0], hm1 = hmfS[g][q * 4 + 1];
                float hm2 = hmfS[g][q * 4 + 2], hm3 = hmfS[g][q * 4 + 3];
                float aw0 = awfS[g][q * 4 + 0], aw1 = awfS[g][q * 4 + 1];
                float aw2 = awfS[g][q * 4 + 2], aw3 = awfS[g][q * 4 + 3];
#pragma unroll
                for (int t = 0; t < 8; ++t) {
                    float v0 = fmaxf(acc[t][0], 0.f), v1 = fmaxf(acc[t][1], 0.f);
                    float v2 = fmaxf(acc[t][2], 0.f), v3 = fmaxf(acc[t][3], 0.f);
                    float hp = hm0 * v0 + hm1 * v1 + hm2 * v2 + hm3 * v3;
                    float ap = aw0 * v0 + aw1 * v1 + aw2 * v2 + aw3 * v3;
                    hp += __shfl_xor(hp, 16); hp += __shfl_xor(hp, 32);
                    ap += __shfl_xor(ap, 16); ap += __shfl_xor(ap, 32);
                    if (l < 16) {
                        H2S[g][(half * 8 + t) * 16 + l]       = f2bs(hp);
                        H2S[g][256 + (half * 8 + t) * 16 + l] = f2bs(ap);
                    }
                }
            }
        }
    }
    // ---- rho: relu([hs;aws] @ r1w + r1b) @ r2w, antisym difference ----
    {
        f32x4 acc0[8], acc1[8];
        initC<8>(acc0, r1b, c16);
        initC<8>(acc1, r1b, c16);
        const int rr = (c16 < 2) ? c16 : 0;
        mm8p2_a16<8>(ws + WS_R1, &H2S[0][0], &H2S[1][0], 256, rr, q, l, acc0, acc1);
        float d0 = 0.f, d1 = 0.f;
        if (q == 0) {
#pragma unroll
            for (int t = 0; t < 8; ++t) {
                float w = r2w[t * 16 + c16];
                d0 = fmaf(fmaxf(acc0[t][0], 0.f) - fmaxf(acc0[t][1], 0.f), w, d0);
                d1 = fmaf(fmaxf(acc1[t][0], 0.f) - fmaxf(acc1[t][1], 0.f), w, d1);
            }
        }
#pragma unroll
        for (int off = 32; off > 0; off >>= 1) {
            d0 += __shfl_xor(d0, off);
            d1 += __shfl_xor(d1, off);
        }
        if (l == 0) {
            out[b0]     = 0.5f + 0.5f * tanhf(d0);
            out[b0 + 1] = 0.5f + 0.5f * tanhf(d1);
        }
    }
}

extern "C" void kernel_launch(void* const* d_in, const int* in_sizes, int n_in,
                              void* d_out, int out_size, void* d_ws, size_t ws_size,
                              hipStream_t stream) {
    const float* A         = (const float*)d_in[0];
    const float* X         = (const float*)d_in[1];
    const int*   home_mask = (const int*)  d_in[2];
    const float* We1       = (const float*)d_in[3];
    const float* be1       = (const float*)d_in[4];
    const float* We2       = (const float*)d_in[5];
    const float* be2       = (const float*)d_in[6];
    const float* rgcn_w    = (const float*)d_in[7];
    const float* rgcn_root = (const float*)d_in[8];
    const float* rgcn_b    = (const float*)d_in[9];
    const float* l1w       = (const float*)d_in[10];
    const float* l1b       = (const float*)d_in[11];
    const float* l2w       = (const float*)d_in[12];
    const float* l2b       = (const float*)d_in[13];
    const float* ln_g      = (const float*)d_in[14];
    const float* ln_b      = (const float*)d_in[15];
    const float* p1w       = (const float*)d_in[16];
    const float* p1b       = (const float*)d_in[17];
    const float* p2w       = (const float*)d_in[18];
    const float* p2b       = (const float*)d_in[19];
    const float* r1w       = (const float*)d_in[20];
    const float* r1b       = (const float*)d_in[21];
    const float* r2w       = (const float*)d_in[22];

    short* ws = (short*)d_ws;

    prep_weights<<<776, 64, 0, stream>>>(We1, We2, rgcn_w, rgcn_root,
                                         l1w, l2w, p1w, p2w, r1w, ws);
    gcn_main<<<B_ / 2, 64, 0, stream>>>(A, X, home_mask, be1, be2, rgcn_b,
                                        l1b, l2b, ln_g, ln_b, p1b, p2b,
                                        r1b, r2w, ws, (float*)d_out);
}

// Round 8
// 260.863 us; speedup vs baseline: 1.0315x; 1.0315x over previous
//
#include <hip/hip_runtime.h>
#include <hip/hip_bf16.h>
#include <math.h>

#define B_    4096
#define N_    10
#define DIN_  32
#define D_    128
#define PHI_  256
#define RHO_  128
#define L_    3
#define EPS_  1e-5f

// ---- bf16 helpers (bits in short) ----
__device__ __forceinline__ short f2bs(float f) {            // f32 -> bf16 RNE
    unsigned u = __float_as_uint(f);
    u += 0x7fffu + ((u >> 16) & 1u);
    return (short)(u >> 16);
}
__device__ __forceinline__ float bs2f(short s) {
    return __uint_as_float(((unsigned)(unsigned short)s) << 16);
}
__device__ __forceinline__ short2 f2bs2(float x, float y) { // packed RNE (v_cvt_pk_bf16_f32)
    float2 f; f.x = x; f.y = y;
    __hip_bfloat162 h = __float22bfloat162_rn(f);
    short2 r;
    __builtin_memcpy(&r, &h, 4);
    return r;
}

typedef short bf16x8 __attribute__((ext_vector_type(8)));
typedef float f32x4  __attribute__((ext_vector_type(4)));
typedef float v2f    __attribute__((ext_vector_type(2)));

__device__ __forceinline__ v2f splat2(float s) { v2f r; r.x = s; r.y = s; return r; }
__device__ __forceinline__ v2f fma2(v2f a, v2f b, v2f c) { return __builtin_elementwise_fma(a, b, c); }

// ---- d_ws layout (bf16 elements). Fragment unit = 64 lanes x 8 el = 512 el.
// For matrix W[K][N]: frag (nt,ks) at ((nt*KS+ks)*64+lane)*8, lane holds
// W[ks*32+(lane>>4)*8+j][nt*16+(lane&15)], j=0..7  (B-operand layout, 16x16x32)
#define WS_WE1 0
#define WS_WE2 4096
#define WS_RGW 20480
#define WS_RGR 118784
#define WS_L1  167936
#define WS_L2  217088
#define WS_P1  266240
#define WS_P2  299008
#define WS_R1  364544

// ================= prep kernel: fp32 weights -> bf16 B-fragments ==========
__global__ __launch_bounds__(64)
void prep_weights(const float* __restrict__ We1, const float* __restrict__ We2,
                  const float* __restrict__ rgw, const float* __restrict__ rgr,
                  const float* __restrict__ l1w, const float* __restrict__ l2w,
                  const float* __restrict__ p1w, const float* __restrict__ p2w,
                  const float* __restrict__ r1w, short* __restrict__ ws)
{
    int bi = blockIdx.x, l = threadIdx.x;
    const float* src; int KS, Nw, dstOff, tt;
    if      (bi <   8) { src = We1; KS = 1; Nw = 128; dstOff = WS_WE1; tt = bi; }
    else if (bi <  40) { src = We2; KS = 4; Nw = 128; dstOff = WS_WE2; tt = bi - 8; }
    else if (bi < 232) { int m = (bi - 40) >> 5;  src = rgw + m * 16384; KS = 4; Nw = 128; dstOff = WS_RGW + m * 16384; tt = (bi - 40)  & 31; }
    else if (bi < 328) { int m = (bi - 232) >> 5; src = rgr + m * 16384; KS = 4; Nw = 128; dstOff = WS_RGR + m * 16384; tt = (bi - 232) & 31; }
    else if (bi < 424) { int m = (bi - 328) >> 5; src = l1w + m * 16384; KS = 4; Nw = 128; dstOff = WS_L1  + m * 16384; tt = (bi - 328) & 31; }
    else if (bi < 520) { int m = (bi - 424) >> 5; src = l2w + m * 16384; KS = 4; Nw = 128; dstOff = WS_L2  + m * 16384; tt = (bi - 424) & 31; }
    else if (bi < 584) { src = p1w; KS = 4; Nw = 256; dstOff = WS_P1; tt = bi - 520; }
    else if (bi < 712) { src = p2w; KS = 8; Nw = 256; dstOff = WS_P2; tt = bi - 584; }
    else               { src = r1w; KS = 8; Nw = 128; dstOff = WS_R1; tt = bi - 712; }
    int nt = tt / KS, ks = tt - nt * KS;
    int kbase = ks * 32 + (l >> 4) * 8;
    int col   = nt * 16 + (l & 15);
    union { short s[8]; int4 v; } u;
#pragma unroll
    for (int j = 0; j < 8; ++j)
        u.s[j] = f2bs(src[(size_t)(kbase + j) * Nw + col]);
    *(int4*)(ws + dstOff + ((size_t)tt * 64 + l) * 8) = u.v;
}

// ================= main kernel: 4 waves/block, 1 wave = 1 graph ============
// A-operand layout: lane holds A[m=lane&15][k=(lane>>4)*8+j]; rows >=10 clamped to 9
// C/D layout: col = lane&15, row = (lane>>4)*4 + reg
// __syncthreads() at each weight-matmul entry phase-locks the 4 waves so they
// stream identical B-fragments together -> trailing waves hit L1 not L2.

template<int NT>
__device__ __forceinline__ void initC(f32x4* acc, const float* __restrict__ bias, int c16) {
#pragma unroll
    for (int nt = 0; nt < NT; ++nt) {
        float bv = bias[nt * 16 + c16];
        acc[nt] = (f32x4){bv, bv, bv, bv};
    }
}

// non-pipelined — used for phi/rho
template<int KS, int NT>
__device__ __forceinline__ void mm_a16(const short* __restrict__ Wf, const short* __restrict__ Ab,
                                       int ldA, int mrow, int q, int lane, f32x4* acc) {
#pragma unroll
    for (int ks = 0; ks < KS; ++ks) {
        bf16x8 a = *(const bf16x8*)(Ab + mrow * ldA + ks * 32 + q * 8);
#pragma unroll
        for (int nt = 0; nt < NT; ++nt) {
            bf16x8 bv = *(const bf16x8*)(Wf + ((size_t)(nt * KS + ks) * 64 + lane) * 8);
            acc[nt] = __builtin_amdgcn_mfma_f32_16x16x32_bf16(a, bv, acc[nt], 0, 0, 0);
        }
    }
}

template<int KS, int NT>
__device__ __forceinline__ void mm_a32(const short* __restrict__ Wf, const float* __restrict__ Af,
                                       int ldA, int mrow, int q, int lane, f32x4* acc) {
#pragma unroll
    for (int ks = 0; ks < KS; ++ks) {
        const float* p = Af + mrow * ldA + ks * 32 + q * 8;
        f32x4 x0 = *(const f32x4*)p;
        f32x4 x1 = *(const f32x4*)(p + 4);
        union { short2 p2[4]; bf16x8 v; } a;
        a.p2[0] = f2bs2(x0[0], x0[1]); a.p2[1] = f2bs2(x0[2], x0[3]);
        a.p2[2] = f2bs2(x1[0], x1[1]); a.p2[3] = f2bs2(x1[2], x1[3]);
#pragma unroll
        for (int nt = 0; nt < NT; ++nt) {
            bf16x8 bv = *(const bf16x8*)(Wf + ((size_t)(nt * KS + ks) * 64 + lane) * 8);
            acc[nt] = __builtin_amdgcn_mfma_f32_16x16x32_bf16(a.v, bv, acc[nt], 0, 0, 0);
        }
    }
}

// software-pipelined NT=8: fragments of ks+1 issue before the MFMAs of ks
template<int KS>
__device__ __forceinline__ void mm8p_a16(const short* __restrict__ Wf,
                                         const short* __restrict__ Ab, int ldA,
                                         int mrow, int q, int lane, f32x4* acc)
{
    const short* ap = Ab + mrow * ldA + q * 8;
    const short* wp = Wf + lane * 8;
    bf16x8 acur = *(const bf16x8*)ap;
    bf16x8 bcur[8], bnxt[8];
#pragma unroll
    for (int nt = 0; nt < 8; ++nt) bcur[nt] = *(const bf16x8*)(wp + (size_t)nt * KS * 512);
#pragma unroll
    for (int ks = 0; ks < KS; ++ks) {
        bf16x8 anxt = acur;
#pragma unroll
        for (int nt = 0; nt < 8; ++nt) bnxt[nt] = bcur[nt];
        if (ks + 1 < KS) {
            anxt = *(const bf16x8*)(ap + (ks + 1) * 32);
#pragma unroll
            for (int nt = 0; nt < 8; ++nt)
                bnxt[nt] = *(const bf16x8*)(wp + (size_t)(nt * KS + ks + 1) * 512);
        }
#pragma unroll
        for (int nt = 0; nt < 8; ++nt)
            acc[nt] = __builtin_amdgcn_mfma_f32_16x16x32_bf16(acur, bcur[nt], acc[nt], 0, 0, 0);
        acur = anxt;
#pragma unroll
        for (int nt = 0; nt < 8; ++nt) bcur[nt] = bnxt[nt];
    }
}

template<int KS>
__device__ __forceinline__ void mm8p_a32(const short* __restrict__ Wf,
                                         const float* __restrict__ Af, int ldA,
                                         int mrow, int q, int lane, f32x4* acc)
{
    const float* ap = Af + mrow * ldA + q * 8;
    const short* wp = Wf + lane * 8;
    auto cvt = [](const float* p) {
        f32x4 x0 = *(const f32x4*)p;
        f32x4 x1 = *(const f32x4*)(p + 4);
        union { short2 p2[4]; bf16x8 v; } a;
        a.p2[0] = f2bs2(x0[0], x0[1]); a.p2[1] = f2bs2(x0[2], x0[3]);
        a.p2[2] = f2bs2(x1[0], x1[1]); a.p2[3] = f2bs2(x1[2], x1[3]);
        return a.v;
    };
    bf16x8 acur = cvt(ap);
    bf16x8 bcur[8], bnxt[8];
#pragma unroll
    for (int nt = 0; nt < 8; ++nt) bcur[nt] = *(const bf16x8*)(wp + (size_t)nt * KS * 512);
#pragma unroll
    for (int ks = 0; ks < KS; ++ks) {
        bf16x8 anxt = acur;
#pragma unroll
        for (int nt = 0; nt < 8; ++nt) bnxt[nt] = bcur[nt];
        if (ks + 1 < KS) {
            anxt = cvt(ap + (ks + 1) * 32);
#pragma unroll
            for (int nt = 0; nt < 8; ++nt)
                bnxt[nt] = *(const bf16x8*)(wp + (size_t)(nt * KS + ks + 1) * 512);
        }
#pragma unroll
        for (int nt = 0; nt < 8; ++nt)
            acc[nt] = __builtin_amdgcn_mfma_f32_16x16x32_bf16(acur, bcur[nt], acc[nt], 0, 0, 0);
        acur = anxt;
#pragma unroll
        for (int nt = 0; nt < 8; ++nt) bcur[nt] = bnxt[nt];
    }
}

// store C tiles as bf16 into LDS (row-major, ldD elements), rows >= 10 dropped
template<int NT, bool RELU>
__device__ __forceinline__ void storeC16(const f32x4* acc, short* __restrict__ dst,
                                         int ldD, int q, int c16) {
#pragma unroll
    for (int nt = 0; nt < NT; ++nt) {
#pragma unroll
        for (int i = 0; i < 4; ++i) {
            int r = q * 4 + i;
            if (r < 10) {
                float v = acc[nt][i];
                if (RELU) v = fmaxf(v, 0.f);
                dst[r * ldD + nt * 16 + c16] = f2bs(v);
            }
        }
    }
}

#define HLD  132   // Hf row stride (f32), 528 B — 4-bank row stagger
#define GLD  264   // Gb row stride (bf16), 528 B — slots S0=+0, S1=+136
#define H2LD 136   // H2 row stride (bf16), 272 B — 4-bank row stagger

__global__ __launch_bounds__(256, 2)
void gcn_main(const float* __restrict__ A, const float* __restrict__ X,
              const int* __restrict__ home_mask,
              const float* __restrict__ be1, const float* __restrict__ be2,
              const float* __restrict__ rgcn_b,
              const float* __restrict__ l1b, const float* __restrict__ l2b,
              const float* __restrict__ ln_g, const float* __restrict__ ln_b,
              const float* __restrict__ p1b, const float* __restrict__ p2b,
              const float* __restrict__ r1b, const float* __restrict__ r2w,
              const short* __restrict__ ws, float* __restrict__ out)
{
    const int t    = threadIdx.x;        // 0..255
    const int w    = t >> 6;             // wave id = graph slot 0..3
    const int lane = t & 63;
    const int q    = lane >> 4;
    const int c16  = lane & 15;
    const int mrow = (c16 < 10) ? c16 : 9;     // A-row clamp (C rows>=10 ignored)
    const int b    = blockIdx.x * 4 + w;       // this wave's graph

    // Buffer flow invariant: every phase's write-buffer is disjoint from its
    // read-buffers (per wave). No cross-wave data sharing — barriers below are
    // pure phase-locking for L1 weight-stream locality.
    __shared__ __align__(16) float HfS[4][N_ * HLD];
    __shared__ __align__(16) short GbS[4][N_ * GLD];
    __shared__ __align__(16) short H2S[4][N_ * H2LD];   // H2 out; later RhoS overlay
    __shared__ float AabsS[4][100], M1S[4][100];
    __shared__ float invc0S[4][N_], invc1S[4][N_];
    __shared__ float hmfS[4][16], awfS[4][16];

    short* S0   = &GbS[w][0];      // cols 0..127 of slot 0
    short* S1   = &GbS[w][136];    // slot 1, base 272 B (16-aligned)
    short* RhoS = &H2S[w][0];      // overlay: H2 dead after last agg; rho rows stride 256

    // ---- stage A, home_mask (per wave, own graph) ----
    {
        const float* Ab = A + (size_t)b * 100;
#pragma unroll
        for (int e = lane; e < 100; e += 64) {
            float a = Ab[e];
            AabsS[w][e] = fabsf(a);
            M1S[w][e]  = (a > 0.f) ? 1.f : 0.f;
        }
        if (lane < 16) {
            float hm = 0.f, aw = 0.f;
            if (lane < 10) { hm = (float)home_mask[b * N_ + lane]; aw = 1.f - hm; }
            hmfS[w][lane] = hm; awfS[w][lane] = aw;
        }
        if (lane < 10) {
            float c1 = 0.f;
#pragma unroll
            for (int i = 0; i < 10; ++i) c1 += M1S[w][i * 10 + lane];
            invc1S[w][lane] = 1.f / fmaxf(c1, 1.f);
            invc0S[w][lane] = 1.f / fmaxf(10.f - c1, 1.f);
        }
    }

    __syncthreads();
    // ---- embed1: H1 = relu(X@We1 + be1) -> S0 ----
    {
        f32x4 acc[8];
        initC<8>(acc, be1, c16);
        const float* xg = X + (size_t)b * (N_ * DIN_) + mrow * DIN_ + q * 8;
        f32x4 x0 = *(const f32x4*)xg;
        f32x4 x1 = *(const f32x4*)(xg + 4);
        union { short2 p2[4]; bf16x8 v; } a;
        a.p2[0] = f2bs2(x0[0], x0[1]); a.p2[1] = f2bs2(x0[2], x0[3]);
        a.p2[2] = f2bs2(x1[0], x1[1]); a.p2[3] = f2bs2(x1[2], x1[3]);
#pragma unroll
        for (int nt = 0; nt < 8; ++nt) {
            bf16x8 bv = *(const bf16x8*)(ws + WS_WE1 + ((size_t)nt * 64 + lane) * 8);
            acc[nt] = __builtin_amdgcn_mfma_f32_16x16x32_bf16(a.v, bv, acc[nt], 0, 0, 0);
        }
        storeC16<8, true>(acc, S0, GLD, q, c16);
    }
    __syncthreads();
    // ---- embed2: H = H1@We2 + be2 -> Hf (fp32) [reads S0, writes HfS] ----
    {
        f32x4 acc[8];
        initC<8>(acc, be2, c16);
        mm8p_a16<4>(ws + WS_WE2, S0, GLD, mrow, q, lane, acc);
#pragma unroll
        for (int nt = 0; nt < 8; ++nt)
#pragma unroll
            for (int i = 0; i < 4; ++i) {
                int r = q * 4 + i;
                if (r < 10) HfS[w][r * HLD + nt * 16 + c16] = acc[nt][i];
            }
    }

    const v2f lg2 = *(const v2f*)(ln_g + 2 * lane);
    const v2f lb2 = *(const v2f*)(ln_b + 2 * lane);

    // ---- layers ----
    for (int ll = 0; ll < L_; ++ll) {
        // means [reads HfS; writes S0=mean0, S1=mean1]
        {
            v2f hv[N_];
#pragma unroll
            for (int i = 0; i < N_; ++i) hv[i] = *(const v2f*)(&HfS[w][i * HLD] + 2 * lane);
            v2f st = hv[0];
#pragma unroll
            for (int i = 1; i < N_; ++i) st += hv[i];
#pragma unroll
            for (int j = 0; j < N_; ++j) {
                v2f s1 = splat2(0.f);
#pragma unroll
                for (int i = 0; i < N_; ++i) s1 = fma2(splat2(M1S[w][i * 10 + j]), hv[i], s1);
                v2f m0 = (st - s1) * splat2(invc0S[w][j]);
                v2f m1 = s1 * splat2(invc1S[w][j]);
                *(short2*)(S0 + j * GLD + 2 * lane) = f2bs2(m0.x, m0.y);
                *(short2*)(S1 + j * GLD + 2 * lane) = f2bs2(m1.x, m1.y);
            }
        }
        __syncthreads();
        // H2 = mean0@W0 + mean1@W1 + H@root + b [reads S0,S1,HfS; writes H2S]
        {
            f32x4 acc[8];
            initC<8>(acc, rgcn_b + ll * D_, c16);
            mm8p_a16<4>(ws + WS_RGW + (size_t)(ll * 2 + 0) * 16384, S0, GLD, mrow, q, lane, acc);
            mm8p_a16<4>(ws + WS_RGW + (size_t)(ll * 2 + 1) * 16384, S1, GLD, mrow, q, lane, acc);
            mm8p_a32<4>(ws + WS_RGR + (size_t)ll * 16384, &HfS[w][0], HLD, mrow, q, lane, acc);
            storeC16<8, false>(acc, &H2S[w][0], H2LD, q, c16);
        }
        // agg[i] = sum_j |A[i,j]| * H2[j] + LayerNorm + relu [reads H2S; writes S0]
        {
            v2f ag[N_];
#pragma unroll
            for (int i = 0; i < N_; ++i) ag[i] = splat2(0.f);
#pragma unroll
            for (int j = 0; j < N_; ++j) {
                short2 hh = *(const short2*)(&H2S[w][j * H2LD] + 2 * lane);
                v2f h2; h2.x = bs2f(hh.x); h2.y = bs2f(hh.y);
#pragma unroll
                for (int i = 0; i < N_; ++i)
                    ag[i] = fma2(splat2(AabsS[w][i * 10 + j]), h2, ag[i]);
            }
#pragma unroll
            for (int i = 0; i < N_; ++i) {
                float s  = ag[i].x + ag[i].y;
                float ss = fmaf(ag[i].x, ag[i].x, ag[i].y * ag[i].y);
#pragma unroll
                for (int off = 32; off > 0; off >>= 1) {
                    s  += __shfl_xor(s,  off);
                    ss += __shfl_xor(ss, off);
                }
                float mu   = s * (1.f / 128.f);
                float var  = ss * (1.f / 128.f) - mu * mu;
                float rstd = rsqrtf(var + EPS_);
                v2f v = fma2((ag[i] - splat2(mu)) * splat2(rstd), lg2, lb2);
                *(short2*)(S0 + i * GLD + 2 * lane) = f2bs2(fmaxf(v.x, 0.f), fmaxf(v.y, 0.f));
            }
        }
        __syncthreads();
        // MLP1: relu(LNout @ l1w + l1b) [reads S0; writes S1]
        {
            f32x4 acc[8];
            initC<8>(acc, l1b + ll * D_, c16);
            mm8p_a16<4>(ws + WS_L1 + (size_t)ll * 16384, S0, GLD, mrow, q, lane, acc);
            storeC16<8, true>(acc, S1, GLD, q, c16);
        }
        __syncthreads();
        // MLP2: hidden @ l2w + l2b [reads S1; accumulates into HfS]
        {
            f32x4 acc[8];
            initC<8>(acc, l2b + ll * D_, c16);
            mm8p_a16<4>(ws + WS_L2 + (size_t)ll * 16384, S1, GLD, mrow, q, lane, acc);
#pragma unroll
            for (int nt = 0; nt < 8; ++nt)
#pragma unroll
                for (int i = 0; i < 4; ++i) {
                    int r = q * 4 + i;
                    if (r < 10) HfS[w][r * HLD + nt * 16 + c16] += acc[nt][i];
                }
        }
    }

    __syncthreads();
    // ---- phi1: relu(H @ p1w + p1b) [reads HfS; writes GbS cols 0..255] ----
    {
        f32x4 acc[16];
        initC<16>(acc, p1b, c16);
        mm_a32<4, 16>(ws + WS_P1, &HfS[w][0], HLD, mrow, q, lane, acc);
        storeC16<16, true>(acc, &GbS[w][0], GLD, q, c16);
    }
    __syncthreads();
    // ---- phi2 + masked column sums [reads GbS; writes RhoS(=H2S)] ----
    {
        f32x4 acc[16];
        initC<16>(acc, p2b, c16);
        mm_a16<8, 16>(ws + WS_P2, &GbS[w][0], GLD, mrow, q, lane, acc);
        float hm0 = hmfS[w][q * 4 + 0], hm1 = hmfS[w][q * 4 + 1];
        float hm2 = hmfS[w][q * 4 + 2], hm3 = hmfS[w][q * 4 + 3];
        float aw0 = awfS[w][q * 4 + 0], aw1 = awfS[w][q * 4 + 1];
        float aw2 = awfS[w][q * 4 + 2], aw3 = awfS[w][q * 4 + 3];
#pragma unroll
        for (int tt = 0; tt < 16; ++tt) {
            float v0 = fmaxf(acc[tt][0], 0.f), v1 = fmaxf(acc[tt][1], 0.f);
            float v2 = fmaxf(acc[tt][2], 0.f), v3 = fmaxf(acc[tt][3], 0.f);
            float hp = hm0 * v0 + hm1 * v1 + hm2 * v2 + hm3 * v3;
            float ap = aw0 * v0 + aw1 * v1 + aw2 * v2 + aw3 * v3;
            hp += __shfl_xor(hp, 16); hp += __shfl_xor(hp, 32);
            ap += __shfl_xor(ap, 16); ap += __shfl_xor(ap, 32);
            if (lane < 16) {
                RhoS[tt * 16 + lane]       = f2bs(hp);
                RhoS[256 + tt * 16 + lane] = f2bs(ap);
            }
        }
    }
    __syncthreads();
    // ---- rho: relu([hs;aws] @ r1w + r1b) @ r2w, antisym difference ----
    {
        f32x4 acc[8];
        initC<8>(acc, r1b, c16);
        const int rr = (c16 < 2) ? c16 : 0;
        mm_a16<8, 8>(ws + WS_R1, RhoS, 256, rr, q, lane, acc);
        float d = 0.f;
        if (q == 0) {
#pragma unroll
            for (int tt = 0; tt < 8; ++tt) {
                float vh = fmaxf(acc[tt][0], 0.f);
                float va = fmaxf(acc[tt][1], 0.f);
                d = fmaf(vh - va, r2w[tt * 16 + c16], d);
            }
        }
#pragma unroll
        for (int off = 32; off > 0; off >>= 1) d += __shfl_xor(d, off);
        if (lane == 0) out[b] = 0.5f + 0.5f * tanhf(d);
    }
}

extern "C" void kernel_launch(void* const* d_in, const int* in_sizes, int n_in,
                              void* d_out, int out_size, void* d_ws, size_t ws_size,
                              hipStream_t stream) {
    const float* A         = (const float*)d_in[0];
    const float* X         = (const float*)d_in[1];
    const int*   home_mask = (const int*)  d_in[2];
    const float* We1       = (const float*)d_in[3];
    const float* be1       = (const float*)d_in[4];
    const float* We2       = (const float*)d_in[5];
    const float* be2       = (const float*)d_in[6];
    const float* rgcn_w    = (const float*)d_in[7];
    const float* rgcn_root = (const float*)d_in[8];
    const float* rgcn_b    = (const float*)d_in[9];
    const float* l1w       = (const float*)d_in[10];
    const float* l1b       = (const float*)d_in[11];
    const float* l2w       = (const float*)d_in[12];
    const float* l2b       = (const float*)d_in[13];
    const float* ln_g      = (const float*)d_in[14];
    const float* ln_b      = (const float*)d_in[15];
    const float* p1w       = (const float*)d_in[16];
    const float* p1b       = (const float*)d_in[17];
    const float* p2w       = (const float*)d_in[18];
    const float* p2b       = (const float*)d_in[19];
    const float* r1w       = (const float*)d_in[20];
    const float* r1b       = (const float*)d_in[21];
    const float* r2w       = (const float*)d_in[22];

    short* ws = (short*)d_ws;

    prep_weights<<<776, 64, 0, stream>>>(We1, We2, rgcn_w, rgcn_root,
                                         l1w, l2w, p1w, p2w, r1w, ws);
    gcn_main<<<B_ / 4, 256, 0, stream>>>(A, X, home_mask, be1, be2, rgcn_b,
                                         l1b, l2b, ln_g, ln_b, p1b, p2b,
                                         r1b, r2w, ws, (float*)d_out);
}

// Round 9
// 253.830 us; speedup vs baseline: 1.0601x; 1.0277x over previous
//
#include <hip/hip_runtime.h>
#include <hip/hip_bf16.h>
#include <math.h>

#define B_    4096
#define N_    10
#define DIN_  32
#define D_    128
#define PHI_  256
#define RHO_  128
#define L_    3
#define EPS_  1e-5f

// ---- bf16 helpers (bits in short) ----
__device__ __forceinline__ short f2bs(float f) {            // f32 -> bf16 RNE
    unsigned u = __float_as_uint(f);
    u += 0x7fffu + ((u >> 16) & 1u);
    return (short)(u >> 16);
}
__device__ __forceinline__ float bs2f(short s) {
    return __uint_as_float(((unsigned)(unsigned short)s) << 16);
}
__device__ __forceinline__ short2 f2bs2(float x, float y) { // packed RNE
    float2 f; f.x = x; f.y = y;
    __hip_bfloat162 h = __float22bfloat162_rn(f);
    short2 r;
    __builtin_memcpy(&r, &h, 4);
    return r;
}

typedef short bf16x8 __attribute__((ext_vector_type(8)));
typedef float f32x4  __attribute__((ext_vector_type(4)));
typedef float v2f    __attribute__((ext_vector_type(2)));

__device__ __forceinline__ v2f splat2(float s) { v2f r; r.x = s; r.y = s; return r; }
__device__ __forceinline__ v2f fma2(v2f a, v2f b, v2f c) { return __builtin_elementwise_fma(a, b, c); }

// ---- d_ws layout (bf16 elements). Fragment unit = 64 lanes x 8 el = 512 el (1 KB).
// For matrix W[K][N]: frag (nt,ks) at ((nt*KS+ks)*64+lane)*8, lane holds
// W[ks*32+(lane>>4)*8+j][nt*16+(lane&15)], j=0..7  (B-operand layout, 16x16x32)
#define WS_WE1 0
#define WS_WE2 4096
#define WS_RGW 20480
#define WS_RGR 118784
#define WS_L1  167936
#define WS_L2  217088
#define WS_P1  266240
#define WS_P2  299008
#define WS_R1  364544

// ================= prep kernel: fp32 weights -> bf16 B-fragments ==========
__global__ __launch_bounds__(64)
void prep_weights(const float* __restrict__ We1, const float* __restrict__ We2,
                  const float* __restrict__ rgw, const float* __restrict__ rgr,
                  const float* __restrict__ l1w, const float* __restrict__ l2w,
                  const float* __restrict__ p1w, const float* __restrict__ p2w,
                  const float* __restrict__ r1w, short* __restrict__ ws)
{
    int bi = blockIdx.x, l = threadIdx.x;
    const float* src; int KS, Nw, dstOff, tt;
    if      (bi <   8) { src = We1; KS = 1; Nw = 128; dstOff = WS_WE1; tt = bi; }
    else if (bi <  40) { src = We2; KS = 4; Nw = 128; dstOff = WS_WE2; tt = bi - 8; }
    else if (bi < 232) { int m = (bi - 40) >> 5;  src = rgw + m * 16384; KS = 4; Nw = 128; dstOff = WS_RGW + m * 16384; tt = (bi - 40)  & 31; }
    else if (bi < 328) { int m = (bi - 232) >> 5; src = rgr + m * 16384; KS = 4; Nw = 128; dstOff = WS_RGR + m * 16384; tt = (bi - 232) & 31; }
    else if (bi < 424) { int m = (bi - 328) >> 5; src = l1w + m * 16384; KS = 4; Nw = 128; dstOff = WS_L1  + m * 16384; tt = (bi - 328) & 31; }
    else if (bi < 520) { int m = (bi - 424) >> 5; src = l2w + m * 16384; KS = 4; Nw = 128; dstOff = WS_L2  + m * 16384; tt = (bi - 424) & 31; }
    else if (bi < 584) { src = p1w; KS = 4; Nw = 256; dstOff = WS_P1; tt = bi - 520; }
    else if (bi < 712) { src = p2w; KS = 8; Nw = 256; dstOff = WS_P2; tt = bi - 584; }
    else               { src = r1w; KS = 8; Nw = 128; dstOff = WS_R1; tt = bi - 712; }
    int nt = tt / KS, ks = tt - nt * KS;
    int kbase = ks * 32 + (l >> 4) * 8;
    int col   = nt * 16 + (l & 15);
    union { short s[8]; int4 v; } u;
#pragma unroll
    for (int j = 0; j < 8; ++j)
        u.s[j] = f2bs(src[(size_t)(kbase + j) * Nw + col]);
    *(int4*)(ws + dstOff + ((size_t)tt * 64 + l) * 8) = u.v;
}

// ================= main kernel: 4 waves/block, 1 wave = 1 graph ============
// B-fragments staged global->LDS once per block (shared by 4 waves), 16-frag
// (16 KB) chunks: stage -> __syncthreads (drains DMA) -> MFMA from LDS -> sync.

__device__ __forceinline__ void stage16(const short* g, short* l) {
    __builtin_amdgcn_global_load_lds(
        (const __attribute__((address_space(1))) void*)g,
        (__attribute__((address_space(3))) void*)l, 16, 0, 0);
}

// stage NF fragments (NF in {8,16}); wave w stages NF/4 of them. LDS dst is
// wave-uniform; HW scatters lane i at dst + i*16 B == fragment lane order.
template<int NF>
__device__ __forceinline__ void stageW(const short* __restrict__ src,
                                       short* __restrict__ dst, int w, int lane) {
    constexpr int PER = NF / 4;
#pragma unroll
    for (int k = 0; k < PER; ++k) {
        int f = w * PER + k;
        stage16(src + (size_t)f * 512 + lane * 8, dst + f * 512);
    }
}

template<int NT>
__device__ __forceinline__ void initC(f32x4* acc, const float* __restrict__ bias, int c16) {
#pragma unroll
    for (int nt = 0; nt < NT; ++nt) {
        float bv = bias[nt * 16 + c16];
        acc[nt] = (f32x4){bv, bv, bv, bv};
    }
}

// staged matmul, A from LDS bf16. Chunks of <=16 frags; acc[NTtot].
template<int KS, int NTtot>
__device__ __forceinline__ void mmStaged16(const short* __restrict__ wsrc,
                                           const short* __restrict__ Ab, int ldA,
                                           int mrow, int q, int lane, int w,
                                           short* __restrict__ Wst, f32x4* acc)
{
    constexpr int NTC = ((16 / KS) < NTtot) ? (16 / KS) : NTtot;
    constexpr int NF  = NTC * KS;
    constexpr int NCH = NTtot / NTC;
#pragma unroll
    for (int c = 0; c < NCH; ++c) {
        stageW<NF>(wsrc + (size_t)c * NF * 512, Wst, w, lane);
        __syncthreads();
#pragma unroll
        for (int ks = 0; ks < KS; ++ks) {
            bf16x8 a = *(const bf16x8*)(Ab + mrow * ldA + ks * 32 + q * 8);
#pragma unroll
            for (int nt = 0; nt < NTC; ++nt) {
                bf16x8 bv = *(const bf16x8*)(Wst + ((nt * KS + ks) * 64 + lane) * 8);
                acc[c * NTC + nt] =
                    __builtin_amdgcn_mfma_f32_16x16x32_bf16(a, bv, acc[c * NTC + nt], 0, 0, 0);
            }
        }
        __syncthreads();
    }
}

// staged matmul, A from LDS fp32 (converted per ks)
template<int KS, int NTtot>
__device__ __forceinline__ void mmStaged32(const short* __restrict__ wsrc,
                                           const float* __restrict__ Af, int ldA,
                                           int mrow, int q, int lane, int w,
                                           short* __restrict__ Wst, f32x4* acc)
{
    constexpr int NTC = ((16 / KS) < NTtot) ? (16 / KS) : NTtot;
    constexpr int NF  = NTC * KS;
    constexpr int NCH = NTtot / NTC;
#pragma unroll
    for (int c = 0; c < NCH; ++c) {
        stageW<NF>(wsrc + (size_t)c * NF * 512, Wst, w, lane);
        __syncthreads();
#pragma unroll
        for (int ks = 0; ks < KS; ++ks) {
            const float* p = Af + mrow * ldA + ks * 32 + q * 8;
            f32x4 x0 = *(const f32x4*)p;
            f32x4 x1 = *(const f32x4*)(p + 4);
            union { short2 p2[4]; bf16x8 v; } a;
            a.p2[0] = f2bs2(x0[0], x0[1]); a.p2[1] = f2bs2(x0[2], x0[3]);
            a.p2[2] = f2bs2(x1[0], x1[1]); a.p2[3] = f2bs2(x1[2], x1[3]);
#pragma unroll
            for (int nt = 0; nt < NTC; ++nt) {
                bf16x8 bv = *(const bf16x8*)(Wst + ((nt * KS + ks) * 64 + lane) * 8);
                acc[c * NTC + nt] =
                    __builtin_amdgcn_mfma_f32_16x16x32_bf16(a.v, bv, acc[c * NTC + nt], 0, 0, 0);
            }
        }
        __syncthreads();
    }
}

// store C tiles as bf16 into LDS (row-major, ldD elements), rows >= 10 dropped
template<int NT, bool RELU>
__device__ __forceinline__ void storeC16(const f32x4* acc, short* __restrict__ dst,
                                         int ldD, int q, int c16) {
#pragma unroll
    for (int nt = 0; nt < NT; ++nt) {
#pragma unroll
        for (int i = 0; i < 4; ++i) {
            int r = q * 4 + i;
            if (r < 10) {
                float v = acc[nt][i];
                if (RELU) v = fmaxf(v, 0.f);
                dst[r * ldD + nt * 16 + c16] = f2bs(v);
            }
        }
    }
}

#define HLD  132   // Hf row stride (f32), 528 B — 4-bank row stagger
#define GLD  264   // Gb row stride (bf16), 528 B — slots S0=+0, S1=+136
#define H2LD 136   // H2 row stride (bf16), 272 B — 4-bank row stagger

__global__ __launch_bounds__(256, 2)
void gcn_main(const float* __restrict__ A, const float* __restrict__ X,
              const int* __restrict__ home_mask,
              const float* __restrict__ be1, const float* __restrict__ be2,
              const float* __restrict__ rgcn_b,
              const float* __restrict__ l1b, const float* __restrict__ l2b,
              const float* __restrict__ ln_g, const float* __restrict__ ln_b,
              const float* __restrict__ p1b, const float* __restrict__ p2b,
              const float* __restrict__ r1b, const float* __restrict__ r2w,
              const short* __restrict__ ws, float* __restrict__ out)
{
    const int t    = threadIdx.x;        // 0..255
    const int w    = t >> 6;             // wave id = graph slot 0..3
    const int lane = t & 63;
    const int q    = lane >> 4;
    const int c16  = lane & 15;
    const int mrow = (c16 < 10) ? c16 : 9;     // A-row clamp (C rows>=10 ignored)
    const int b    = blockIdx.x * 4 + w;       // this wave's graph

    // Per-wave activation buffers (disjoint read/write sets per phase).
    // WstS is the block-shared 16 KB weight staging buffer.
    __shared__ __align__(16) float HfS[4][N_ * HLD];
    __shared__ __align__(16) short GbS[4][N_ * GLD];
    __shared__ __align__(16) short H2S[4][N_ * H2LD];   // H2 out; later RhoS overlay
    __shared__ __align__(16) short WstS[16 * 512];      // 16 KB staging
    __shared__ float AabsS[4][100], M1S[4][100];
    __shared__ float invc0S[4][N_], invc1S[4][N_];
    __shared__ float hmfS[4][16], awfS[4][16];

    short* S0   = &GbS[w][0];      // cols 0..127 of slot 0
    short* S1   = &GbS[w][136];    // slot 1, base 272 B (16-aligned)
    short* RhoS = &H2S[w][0];      // overlay: H2 dead after last agg; rho rows stride 256

    // ---- stage A, home_mask (per wave, own graph) ----
    {
        const float* Ab = A + (size_t)b * 100;
#pragma unroll
        for (int e = lane; e < 100; e += 64) {
            float a = Ab[e];
            AabsS[w][e] = fabsf(a);
            M1S[w][e]  = (a > 0.f) ? 1.f : 0.f;
        }
        if (lane < 16) {
            float hm = 0.f, aw = 0.f;
            if (lane < 10) { hm = (float)home_mask[b * N_ + lane]; aw = 1.f - hm; }
            hmfS[w][lane] = hm; awfS[w][lane] = aw;
        }
        if (lane < 10) {
            float c1 = 0.f;
#pragma unroll
            for (int i = 0; i < 10; ++i) c1 += M1S[w][i * 10 + lane];
            invc1S[w][lane] = 1.f / fmaxf(c1, 1.f);
            invc0S[w][lane] = 1.f / fmaxf(10.f - c1, 1.f);
        }
    }

    // ---- embed1: H1 = relu(X@We1 + be1) -> S0 (We1 = 8 frags, one stage) ----
    stageW<8>(ws + WS_WE1, WstS, w, lane);
    __syncthreads();
    {
        f32x4 acc[8];
        initC<8>(acc, be1, c16);
        const float* xg = X + (size_t)b * (N_ * DIN_) + mrow * DIN_ + q * 8;
        f32x4 x0 = *(const f32x4*)xg;
        f32x4 x1 = *(const f32x4*)(xg + 4);
        union { short2 p2[4]; bf16x8 v; } a;
        a.p2[0] = f2bs2(x0[0], x0[1]); a.p2[1] = f2bs2(x0[2], x0[3]);
        a.p2[2] = f2bs2(x1[0], x1[1]); a.p2[3] = f2bs2(x1[2], x1[3]);
#pragma unroll
        for (int nt = 0; nt < 8; ++nt) {
            bf16x8 bv = *(const bf16x8*)(WstS + (nt * 64 + lane) * 8);
            acc[nt] = __builtin_amdgcn_mfma_f32_16x16x32_bf16(a.v, bv, acc[nt], 0, 0, 0);
        }
        storeC16<8, true>(acc, S0, GLD, q, c16);
    }
    __syncthreads();
    // ---- embed2: H = H1@We2 + be2 -> Hf (fp32) ----
    {
        f32x4 acc[8];
        initC<8>(acc, be2, c16);
        mmStaged16<4, 8>(ws + WS_WE2, S0, GLD, mrow, q, lane, w, WstS, acc);
#pragma unroll
        for (int nt = 0; nt < 8; ++nt)
#pragma unroll
            for (int i = 0; i < 4; ++i) {
                int r = q * 4 + i;
                if (r < 10) HfS[w][r * HLD + nt * 16 + c16] = acc[nt][i];
            }
    }

    const v2f lg2 = *(const v2f*)(ln_g + 2 * lane);
    const v2f lb2 = *(const v2f*)(ln_b + 2 * lane);

    // ---- layers ----
    for (int ll = 0; ll < L_; ++ll) {
        // means [reads HfS; writes S0=mean0, S1=mean1]
        {
            v2f hv[N_];
#pragma unroll
            for (int i = 0; i < N_; ++i) hv[i] = *(const v2f*)(&HfS[w][i * HLD] + 2 * lane);
            v2f st = hv[0];
#pragma unroll
            for (int i = 1; i < N_; ++i) st += hv[i];
#pragma unroll
            for (int j = 0; j < N_; ++j) {
                v2f s1 = splat2(0.f);
#pragma unroll
                for (int i = 0; i < N_; ++i) s1 = fma2(splat2(M1S[w][i * 10 + j]), hv[i], s1);
                v2f m0 = (st - s1) * splat2(invc0S[w][j]);
                v2f m1 = s1 * splat2(invc1S[w][j]);
                *(short2*)(S0 + j * GLD + 2 * lane) = f2bs2(m0.x, m0.y);
                *(short2*)(S1 + j * GLD + 2 * lane) = f2bs2(m1.x, m1.y);
            }
        }
        // H2 = mean0@W0 + mean1@W1 + H@root + b [writes H2S]
        {
            f32x4 acc[8];
            initC<8>(acc, rgcn_b + ll * D_, c16);
            mmStaged16<4, 8>(ws + WS_RGW + (size_t)(ll * 2 + 0) * 16384, S0, GLD, mrow, q, lane, w, WstS, acc);
            mmStaged16<4, 8>(ws + WS_RGW + (size_t)(ll * 2 + 1) * 16384, S1, GLD, mrow, q, lane, w, WstS, acc);
            mmStaged32<4, 8>(ws + WS_RGR + (size_t)ll * 16384, &HfS[w][0], HLD, mrow, q, lane, w, WstS, acc);
            storeC16<8, false>(acc, &H2S[w][0], H2LD, q, c16);
        }
        // agg[i] = sum_j |A[i,j]| * H2[j] + LayerNorm + relu [reads H2S; writes S0]
        {
            v2f ag[N_];
#pragma unroll
            for (int i = 0; i < N_; ++i) ag[i] = splat2(0.f);
#pragma unroll
            for (int j = 0; j < N_; ++j) {
                short2 hh = *(const short2*)(&H2S[w][j * H2LD] + 2 * lane);
                v2f h2; h2.x = bs2f(hh.x); h2.y = bs2f(hh.y);
#pragma unroll
                for (int i = 0; i < N_; ++i)
                    ag[i] = fma2(splat2(AabsS[w][i * 10 + j]), h2, ag[i]);
            }
#pragma unroll
            for (int i = 0; i < N_; ++i) {
                float s  = ag[i].x + ag[i].y;
                float ss = fmaf(ag[i].x, ag[i].x, ag[i].y * ag[i].y);
#pragma unroll
                for (int off = 32; off > 0; off >>= 1) {
                    s  += __shfl_xor(s,  off);
                    ss += __shfl_xor(ss, off);
                }
                float mu   = s * (1.f / 128.f);
                float var  = ss * (1.f / 128.f) - mu * mu;
                float rstd = rsqrtf(var + EPS_);
                v2f v = fma2((ag[i] - splat2(mu)) * splat2(rstd), lg2, lb2);
                *(short2*)(S0 + i * GLD + 2 * lane) = f2bs2(fmaxf(v.x, 0.f), fmaxf(v.y, 0.f));
            }
        }
        // MLP1: relu(LNout @ l1w + l1b) [reads S0; writes S1]
        {
            f32x4 acc[8];
            initC<8>(acc, l1b + ll * D_, c16);
            mmStaged16<4, 8>(ws + WS_L1 + (size_t)ll * 16384, S0, GLD, mrow, q, lane, w, WstS, acc);
            storeC16<8, true>(acc, S1, GLD, q, c16);
        }
        // MLP2: hidden @ l2w + l2b [reads S1; accumulates into HfS]
        {
            f32x4 acc[8];
            initC<8>(acc, l2b + ll * D_, c16);
            mmStaged16<4, 8>(ws + WS_L2 + (size_t)ll * 16384, S1, GLD, mrow, q, lane, w, WstS, acc);
#pragma unroll
            for (int nt = 0; nt < 8; ++nt)
#pragma unroll
                for (int i = 0; i < 4; ++i) {
                    int r = q * 4 + i;
                    if (r < 10) HfS[w][r * HLD + nt * 16 + c16] += acc[nt][i];
                }
        }
    }

    // ---- phi1: relu(H @ p1w + p1b) [reads HfS; writes GbS cols 0..255] ----
    {
        f32x4 acc[16];
        initC<16>(acc, p1b, c16);
        mmStaged32<4, 16>(ws + WS_P1, &HfS[w][0], HLD, mrow, q, lane, w, WstS, acc);
        storeC16<16, true>(acc, &GbS[w][0], GLD, q, c16);
    }
    // ---- phi2 + masked column sums [reads GbS; writes RhoS(=H2S)] ----
    {
        f32x4 acc[16];
        initC<16>(acc, p2b, c16);
        mmStaged16<8, 16>(ws + WS_P2, &GbS[w][0], GLD, mrow, q, lane, w, WstS, acc);
        float hm0 = hmfS[w][q * 4 + 0], hm1 = hmfS[w][q * 4 + 1];
        float hm2 = hmfS[w][q * 4 + 2], hm3 = hmfS[w][q * 4 + 3];
        float aw0 = awfS[w][q * 4 + 0], aw1 = awfS[w][q * 4 + 1];
        float aw2 = awfS[w][q * 4 + 2], aw3 = awfS[w][q * 4 + 3];
#pragma unroll
        for (int tt = 0; tt < 16; ++tt) {
            float v0 = fmaxf(acc[tt][0], 0.f), v1 = fmaxf(acc[tt][1], 0.f);
            float v2 = fmaxf(acc[tt][2], 0.f), v3 = fmaxf(acc[tt][3], 0.f);
            float hp = hm0 * v0 + hm1 * v1 + hm2 * v2 + hm3 * v3;
            float ap = aw0 * v0 + aw1 * v1 + aw2 * v2 + aw3 * v3;
            hp += __shfl_xor(hp, 16); hp += __shfl_xor(hp, 32);
            ap += __shfl_xor(ap, 16); ap += __shfl_xor(ap, 32);
            if (lane < 16) {
                RhoS[tt * 16 + lane]       = f2bs(hp);
                RhoS[256 + tt * 16 + lane] = f2bs(ap);
            }
        }
    }
    // ---- rho: relu([hs;aws] @ r1w + r1b) @ r2w, antisym difference ----
    {
        f32x4 acc[8];
        initC<8>(acc, r1b, c16);
        const int rr = (c16 < 2) ? c16 : 0;
        mmStaged16<8, 8>(ws + WS_R1, RhoS, 256, rr, q, lane, w, WstS, acc);
        float d = 0.f;
        if (q == 0) {
#pragma unroll
            for (int tt = 0; tt < 8; ++tt) {
                float vh = fmaxf(acc[tt][0], 0.f);
                float va = fmaxf(acc[tt][1], 0.f);
                d = fmaf(vh - va, r2w[tt * 16 + c16], d);
            }
        }
#pragma unroll
        for (int off = 32; off > 0; off >>= 1) d += __shfl_xor(d, off);
        if (lane == 0) out[b] = 0.5f + 0.5f * tanhf(d);
    }
}

extern "C" void kernel_launch(void* const* d_in, const int* in_sizes, int n_in,
                              void* d_out, int out_size, void* d_ws, size_t ws_size,
                              hipStream_t stream) {
    const float* A         = (const float*)d_in[0];
    const float* X         = (const float*)d_in[1];
    const int*   home_mask = (const int*)  d_in[2];
    const float* We1       = (const float*)d_in[3];
    const float* be1       = (const float*)d_in[4];
    const float* We2       = (const float*)d_in[5];
    const float* be2       = (const float*)d_in[6];
    const float* rgcn_w    = (const float*)d_in[7];
    const float* rgcn_root = (const float*)d_in[8];
    const float* rgcn_b    = (const float*)d_in[9];
    const float* l1w       = (const float*)d_in[10];
    const float* l1b       = (const float*)d_in[11];
    const float* l2w       = (const float*)d_in[12];
    const float* l2b       = (const float*)d_in[13];
    const float* ln_g      = (const float*)d_in[14];
    const float* ln_b      = (const float*)d_in[15];
    const float* p1w       = (const float*)d_in[16];
    const float* p1b       = (const float*)d_in[17];
    const float* p2w       = (const float*)d_in[18];
    const float* p2b       = (const float*)d_in[19];
    const float* r1w       = (const float*)d_in[20];
    const float* r1b       = (const float*)d_in[21];
    const float* r2w       = (const float*)d_in[22];

    short* ws = (short*)d_ws;

    prep_weights<<<776, 64, 0, stream>>>(We1, We2, rgcn_w, rgcn_root,
                                         l1w, l2w, p1w, p2w, r1w, ws);
    gcn_main<<<B_ / 4, 256, 0, stream>>>(A, X, home_mask, be1, be2, rgcn_b,
                                         l1b, l2b, ln_g, ln_b, p1b, p2b,
                                         r1b, r2w, ws, (float*)d_out);
}

// Round 10
// 253.105 us; speedup vs baseline: 1.0631x; 1.0029x over previous
//
#include <hip/hip_runtime.h>
#include <hip/hip_bf16.h>
#include <math.h>

#define B_    4096
#define N_    10
#define DIN_  32
#define D_    128
#define PHI_  256
#define RHO_  128
#define L_    3
#define EPS_  1e-5f

// ---- bf16 helpers (bits in short) ----
__device__ __forceinline__ short f2bs(float f) {            // f32 -> bf16 RNE
    unsigned u = __float_as_uint(f);
    u += 0x7fffu + ((u >> 16) & 1u);
    return (short)(u >> 16);
}
__device__ __forceinline__ float bs2f(short s) {
    return __uint_as_float(((unsigned)(unsigned short)s) << 16);
}
__device__ __forceinline__ short2 f2bs2(float x, float y) { // packed RNE
    float2 f; f.x = x; f.y = y;
    __hip_bfloat162 h = __float22bfloat162_rn(f);
    short2 r;
    __builtin_memcpy(&r, &h, 4);
    return r;
}

typedef short bf16x8 __attribute__((ext_vector_type(8)));
typedef float f32x4  __attribute__((ext_vector_type(4)));
typedef float v2f    __attribute__((ext_vector_type(2)));

__device__ __forceinline__ v2f splat2(float s) { v2f r; r.x = s; r.y = s; return r; }
__device__ __forceinline__ v2f fma2(v2f a, v2f b, v2f c) { return __builtin_elementwise_fma(a, b, c); }

// ---- d_ws layout (bf16 elements). Fragment unit = 64 lanes x 8 el = 512 el (1 KB).
// For matrix W[K][N]: frag (nt,ks) at ((nt*KS+ks)*64+lane)*8, lane holds
// W[ks*32+(lane>>4)*8+j][nt*16+(lane&15)], j=0..7  (B-operand layout, 16x16x32)
#define WS_WE1 0
#define WS_WE2 4096
#define WS_RGW 20480
#define WS_RGR 118784
#define WS_L1  167936
#define WS_L2  217088
#define WS_P1  266240
#define WS_P2  299008
#define WS_R1  364544

// ================= prep kernel: fp32 weights -> bf16 B-fragments ==========
__global__ __launch_bounds__(64)
void prep_weights(const float* __restrict__ We1, const float* __restrict__ We2,
                  const float* __restrict__ rgw, const float* __restrict__ rgr,
                  const float* __restrict__ l1w, const float* __restrict__ l2w,
                  const float* __restrict__ p1w, const float* __restrict__ p2w,
                  const float* __restrict__ r1w, short* __restrict__ ws)
{
    int bi = blockIdx.x, l = threadIdx.x;
    const float* src; int KS, Nw, dstOff, tt;
    if      (bi <   8) { src = We1; KS = 1; Nw = 128; dstOff = WS_WE1; tt = bi; }
    else if (bi <  40) { src = We2; KS = 4; Nw = 128; dstOff = WS_WE2; tt = bi - 8; }
    else if (bi < 232) { int m = (bi - 40) >> 5;  src = rgw + m * 16384; KS = 4; Nw = 128; dstOff = WS_RGW + m * 16384; tt = (bi - 40)  & 31; }
    else if (bi < 328) { int m = (bi - 232) >> 5; src = rgr + m * 16384; KS = 4; Nw = 128; dstOff = WS_RGR + m * 16384; tt = (bi - 232) & 31; }
    else if (bi < 424) { int m = (bi - 328) >> 5; src = l1w + m * 16384; KS = 4; Nw = 128; dstOff = WS_L1  + m * 16384; tt = (bi - 328) & 31; }
    else if (bi < 520) { int m = (bi - 424) >> 5; src = l2w + m * 16384; KS = 4; Nw = 128; dstOff = WS_L2  + m * 16384; tt = (bi - 424) & 31; }
    else if (bi < 584) { src = p1w; KS = 4; Nw = 256; dstOff = WS_P1; tt = bi - 520; }
    else if (bi < 712) { src = p2w; KS = 8; Nw = 256; dstOff = WS_P2; tt = bi - 584; }
    else               { src = r1w; KS = 8; Nw = 128; dstOff = WS_R1; tt = bi - 712; }
    int nt = tt / KS, ks = tt - nt * KS;
    int kbase = ks * 32 + (l >> 4) * 8;
    int col   = nt * 16 + (l & 15);
    union { short s[8]; int4 v; } u;
#pragma unroll
    for (int j = 0; j < 8; ++j)
        u.s[j] = f2bs(src[(size_t)(kbase + j) * Nw + col]);
    *(int4*)(ws + dstOff + ((size_t)tt * 64 + l) * 8) = u.v;
}

// ================= main kernel: 1 wave = 1 graph, register-diet ===========
// A-operand layout: lane holds A[m=lane&15][k=(lane>>4)*8+j]; rows >=10 clamped to 9
// C/D layout: col = lane&15, row = (lane>>4)*4 + reg
// B streamed from L2 through a 6-deep register ring (24 VGPRs, not 64).

template<int NT>
__device__ __forceinline__ void initC(f32x4* acc, const float* __restrict__ bias, int c16) {
#pragma unroll
    for (int nt = 0; nt < NT; ++nt) {
        float bv = bias[nt * 16 + c16];
        acc[nt] = (f32x4){bv, bv, bv, bv};
    }
}

// rolling-ring matmul, A pre-built in a[KS] registers
template<int KS, int NT>
__device__ __forceinline__ void mmRing(const short* __restrict__ Wf, const bf16x8* a,
                                       int lane, f32x4* acc)
{
    const short* wp = Wf + lane * 8;
    constexpr int NFR = KS * NT;
    constexpr int RD  = (6 < NFR) ? 6 : NFR;
    bf16x8 ring[RD];
#pragma unroll
    for (int i = 0; i < RD; ++i) ring[i] = *(const bf16x8*)(wp + (size_t)i * 512);
#pragma unroll
    for (int f = 0; f < NFR; ++f) {
        bf16x8 b = ring[f % RD];
        if (f + RD < NFR) ring[f % RD] = *(const bf16x8*)(wp + (size_t)(f + RD) * 512);
        acc[f / KS] = __builtin_amdgcn_mfma_f32_16x16x32_bf16(a[f % KS], b, acc[f / KS], 0, 0, 0);
    }
}

template<int KS, int NT>
__device__ __forceinline__ void mmR_a16(const short* __restrict__ Wf,
                                        const short* __restrict__ Ab, int ldA,
                                        int mrow, int q, int lane, f32x4* acc)
{
    const short* ap = Ab + mrow * ldA + q * 8;
    bf16x8 a[KS];
#pragma unroll
    for (int k = 0; k < KS; ++k) a[k] = *(const bf16x8*)(ap + k * 32);
    mmRing<KS, NT>(Wf, a, lane, acc);
}

template<int KS, int NT>
__device__ __forceinline__ void mmR_a32(const short* __restrict__ Wf,
                                        const float* __restrict__ Af, int ldA,
                                        int mrow, int q, int lane, f32x4* acc)
{
    const float* ap = Af + mrow * ldA + q * 8;
    bf16x8 a[KS];
#pragma unroll
    for (int k = 0; k < KS; ++k) {
        f32x4 x0 = *(const f32x4*)(ap + k * 32);
        f32x4 x1 = *(const f32x4*)(ap + k * 32 + 4);
        union { short2 p2[4]; bf16x8 v; } u;
        u.p2[0] = f2bs2(x0[0], x0[1]); u.p2[1] = f2bs2(x0[2], x0[3]);
        u.p2[2] = f2bs2(x1[0], x1[1]); u.p2[3] = f2bs2(x1[2], x1[3]);
        a[k] = u.v;
    }
    mmRing<KS, NT>(Wf, a, lane, acc);
}

// store C tiles as bf16 into LDS (row-major, ldD elements), rows >= 10 dropped
template<int NT, bool RELU>
__device__ __forceinline__ void storeC16(const f32x4* acc, short* __restrict__ dst,
                                         int ldD, int q, int c16) {
#pragma unroll
    for (int nt = 0; nt < NT; ++nt) {
#pragma unroll
        for (int i = 0; i < 4; ++i) {
            int r = q * 4 + i;
            if (r < 10) {
                float v = acc[nt][i];
                if (RELU) v = fmaxf(v, 0.f);
                dst[r * ldD + nt * 16 + c16] = f2bs(v);
            }
        }
    }
}

#define HLD  132   // Hf row stride (f32), 528 B — 4-bank row stagger
#define GLD  264   // Gb row stride (bf16), 528 B — slots S0=+0, S1=+136
#define H2LD 136   // H2 row stride (bf16), 272 B — 4-bank row stagger

__global__ __launch_bounds__(64, 3)
void gcn_main(const float* __restrict__ A, const float* __restrict__ X,
              const int* __restrict__ home_mask,
              const float* __restrict__ be1, const float* __restrict__ be2,
              const float* __restrict__ rgcn_b,
              const float* __restrict__ l1b, const float* __restrict__ l2b,
              const float* __restrict__ ln_g, const float* __restrict__ ln_b,
              const float* __restrict__ p1b, const float* __restrict__ p2b,
              const float* __restrict__ r1b, const float* __restrict__ r2w,
              const short* __restrict__ ws, float* __restrict__ out)
{
    const int b    = blockIdx.x;
    const int lane = threadIdx.x;      // 0..63
    const int q    = lane >> 4;
    const int c16  = lane & 15;
    const int mrow = (c16 < 10) ? c16 : 9;    // A-row clamp (C rows>=10 ignored)

    // Buffer flow invariant: every phase's write-buffer is disjoint from its
    // read-buffers (no in-place phases).
    __shared__ __align__(16) float HfS[N_ * HLD];     // residual H, fp32
    __shared__ __align__(16) short GbS[N_ * GLD];     // S0/S1 slots + phi1 rows
    __shared__ __align__(16) short H2S[N_ * H2LD];    // H2 out; later RhoS overlay
    __shared__ float AabsS[100], M1S[100];
    __shared__ float invc0S[N_], invc1S[N_];
    __shared__ float hmfS[16], awfS[16];

    short* S0   = GbS;          // cols 0..127 of slot 0
    short* S1   = GbS + 136;    // slot 1, base 272 B (16-aligned)
    short* RhoS = H2S;          // overlay: H2 dead after last agg; rho rows stride 256

    // ---- stage A, home_mask ----
    {
        const float* Ab = A + (size_t)b * 100;
#pragma unroll
        for (int e = lane; e < 100; e += 64) {
            float a = Ab[e];
            AabsS[e] = fabsf(a);
            M1S[e]  = (a > 0.f) ? 1.f : 0.f;
        }
        if (lane < 16) {
            float hm = 0.f, aw = 0.f;
            if (lane < 10) { hm = (float)home_mask[b * N_ + lane]; aw = 1.f - hm; }
            hmfS[lane] = hm; awfS[lane] = aw;
        }
        if (lane < 10) {
            float c1 = 0.f;
#pragma unroll
            for (int i = 0; i < 10; ++i) c1 += M1S[i * 10 + lane];
            invc1S[lane] = 1.f / fmaxf(c1, 1.f);
            invc0S[lane] = 1.f / fmaxf(10.f - c1, 1.f);
        }
    }

    // ---- embed1: H1 = relu(X@We1 + be1) -> S0 ----
    {
        f32x4 acc[8];
        initC<8>(acc, be1, c16);
        const float* xg = X + (size_t)b * (N_ * DIN_) + mrow * DIN_ + q * 8;
        f32x4 x0 = *(const f32x4*)xg;
        f32x4 x1 = *(const f32x4*)(xg + 4);
        union { short2 p2[4]; bf16x8 v; } a;
        a.p2[0] = f2bs2(x0[0], x0[1]); a.p2[1] = f2bs2(x0[2], x0[3]);
        a.p2[2] = f2bs2(x1[0], x1[1]); a.p2[3] = f2bs2(x1[2], x1[3]);
        bf16x8 av[1]; av[0] = a.v;
        mmRing<1, 8>(ws + WS_WE1, av, lane, acc);
        storeC16<8, true>(acc, S0, GLD, q, c16);
    }
    // ---- embed2: H = H1@We2 + be2 -> Hf (fp32) [reads S0, writes HfS] ----
    {
        f32x4 acc[8];
        initC<8>(acc, be2, c16);
        mmR_a16<4, 8>(ws + WS_WE2, S0, GLD, mrow, q, lane, acc);
#pragma unroll
        for (int nt = 0; nt < 8; ++nt)
#pragma unroll
            for (int i = 0; i < 4; ++i) {
                int r = q * 4 + i;
                if (r < 10) HfS[r * HLD + nt * 16 + c16] = acc[nt][i];
            }
    }

    const v2f lg2 = *(const v2f*)(ln_g + 2 * lane);
    const v2f lb2 = *(const v2f*)(ln_b + 2 * lane);

    // ---- layers ----
    for (int ll = 0; ll < L_; ++ll) {
        // means [reads HfS; writes S0=mean0, S1=mean1]
        {
            v2f hv[N_];
#pragma unroll
            for (int i = 0; i < N_; ++i) hv[i] = *(const v2f*)(HfS + i * HLD + 2 * lane);
            v2f st = hv[0];
#pragma unroll
            for (int i = 1; i < N_; ++i) st += hv[i];
#pragma unroll
            for (int j = 0; j < N_; ++j) {
                v2f s1 = splat2(0.f);
#pragma unroll
                for (int i = 0; i < N_; ++i) s1 = fma2(splat2(M1S[i * 10 + j]), hv[i], s1);
                v2f m0 = (st - s1) * splat2(invc0S[j]);
                v2f m1 = s1 * splat2(invc1S[j]);
                *(short2*)(S0 + j * GLD + 2 * lane) = f2bs2(m0.x, m0.y);
                *(short2*)(S1 + j * GLD + 2 * lane) = f2bs2(m1.x, m1.y);
            }
        }
        // H2 = mean0@W0 + mean1@W1 + H@root + b [reads S0,S1,HfS; writes H2S]
        {
            f32x4 acc[8];
            initC<8>(acc, rgcn_b + ll * D_, c16);
            mmR_a16<4, 8>(ws + WS_RGW + (size_t)(ll * 2 + 0) * 16384, S0, GLD, mrow, q, lane, acc);
            mmR_a16<4, 8>(ws + WS_RGW + (size_t)(ll * 2 + 1) * 16384, S1, GLD, mrow, q, lane, acc);
            mmR_a32<4, 8>(ws + WS_RGR + (size_t)ll * 16384, HfS, HLD, mrow, q, lane, acc);
            storeC16<8, false>(acc, H2S, H2LD, q, c16);
        }
        // agg[i] = sum_j |A[i,j]| * H2[j] + LayerNorm + relu [reads H2S; writes S0]
        {
            v2f ag[N_];
#pragma unroll
            for (int i = 0; i < N_; ++i) ag[i] = splat2(0.f);
#pragma unroll
            for (int j = 0; j < N_; ++j) {
                short2 hh = *(const short2*)(H2S + j * H2LD + 2 * lane);
                v2f h2; h2.x = bs2f(hh.x); h2.y = bs2f(hh.y);
#pragma unroll
                for (int i = 0; i < N_; ++i)
                    ag[i] = fma2(splat2(AabsS[i * 10 + j]), h2, ag[i]);
            }
#pragma unroll
            for (int i = 0; i < N_; ++i) {
                float s  = ag[i].x + ag[i].y;
                float ss = fmaf(ag[i].x, ag[i].x, ag[i].y * ag[i].y);
#pragma unroll
                for (int off = 32; off > 0; off >>= 1) {
                    s  += __shfl_xor(s,  off);
                    ss += __shfl_xor(ss, off);
                }
                float mu   = s * (1.f / 128.f);
                float var  = ss * (1.f / 128.f) - mu * mu;
                float rstd = rsqrtf(var + EPS_);
                v2f v = fma2((ag[i] - splat2(mu)) * splat2(rstd), lg2, lb2);
                *(short2*)(S0 + i * GLD + 2 * lane) = f2bs2(fmaxf(v.x, 0.f), fmaxf(v.y, 0.f));
            }
        }
        // MLP1: relu(LNout @ l1w + l1b) [reads S0; writes S1]
        {
            f32x4 acc[8];
            initC<8>(acc, l1b + ll * D_, c16);
            mmR_a16<4, 8>(ws + WS_L1 + (size_t)ll * 16384, S0, GLD, mrow, q, lane, acc);
            storeC16<8, true>(acc, S1, GLD, q, c16);
        }
        // MLP2: hidden @ l2w + l2b [reads S1; accumulates into HfS]
        {
            f32x4 acc[8];
            initC<8>(acc, l2b + ll * D_, c16);
            mmR_a16<4, 8>(ws + WS_L2 + (size_t)ll * 16384, S1, GLD, mrow, q, lane, acc);
#pragma unroll
            for (int nt = 0; nt < 8; ++nt)
#pragma unroll
                for (int i = 0; i < 4; ++i) {
                    int r = q * 4 + i;
                    if (r < 10) HfS[r * HLD + nt * 16 + c16] += acc[nt][i];
                }
        }
    }

    // ---- phi1: relu(H @ p1w + p1b) [reads HfS; writes GbS cols 0..255] ----
    {
        f32x4 acc[8];
        initC<8>(acc, p1b, c16);
        mmR_a32<4, 8>(ws + WS_P1, HfS, HLD, mrow, q, lane, acc);
        storeC16<8, true>(acc, GbS, GLD, q, c16);
        initC<8>(acc, p1b + 128, c16);
        mmR_a32<4, 8>(ws + WS_P1 + 8 * 4 * 512, HfS, HLD, mrow, q, lane, acc);
        storeC16<8, true>(acc, GbS + 128, GLD, q, c16);
    }
    // ---- phi2 + masked column sums [reads GbS; writes RhoS(=H2S)] ----
    {
        float hm0 = hmfS[q * 4 + 0], hm1 = hmfS[q * 4 + 1];
        float hm2 = hmfS[q * 4 + 2], hm3 = hmfS[q * 4 + 3];
        float aw0 = awfS[q * 4 + 0], aw1 = awfS[q * 4 + 1];
        float aw2 = awfS[q * 4 + 2], aw3 = awfS[q * 4 + 3];
#pragma unroll
        for (int half = 0; half < 2; ++half) {
            f32x4 acc[8];
            initC<8>(acc, p2b + half * 128, c16);
            mmR_a16<8, 8>(ws + WS_P2 + (size_t)half * 8 * 8 * 512, GbS, GLD, mrow, q, lane, acc);
#pragma unroll
            for (int tt = 0; tt < 8; ++tt) {
                float v0 = fmaxf(acc[tt][0], 0.f), v1 = fmaxf(acc[tt][1], 0.f);
                float v2 = fmaxf(acc[tt][2], 0.f), v3 = fmaxf(acc[tt][3], 0.f);
                float hp = hm0 * v0 + hm1 * v1 + hm2 * v2 + hm3 * v3;
                float ap = aw0 * v0 + aw1 * v1 + aw2 * v2 + aw3 * v3;
                hp += __shfl_xor(hp, 16); hp += __shfl_xor(hp, 32);
                ap += __shfl_xor(ap, 16); ap += __shfl_xor(ap, 32);
                if (lane < 16) {
                    RhoS[(half * 8 + tt) * 16 + lane]       = f2bs(hp);
                    RhoS[256 + (half * 8 + tt) * 16 + lane] = f2bs(ap);
                }
            }
        }
    }
    // ---- rho: relu([hs;aws] @ r1w + r1b) @ r2w, antisym difference ----
    {
        f32x4 acc[8];
        initC<8>(acc, r1b, c16);
        const int rr = (c16 < 2) ? c16 : 0;
        mmR_a16<8, 8>(ws + WS_R1, RhoS, 256, rr, q, lane, acc);
        float d = 0.f;
        if (q == 0) {
#pragma unroll
            for (int tt = 0; tt < 8; ++tt) {
                float vh = fmaxf(acc[tt][0], 0.f);
                float va = fmaxf(acc[tt][1], 0.f);
                d = fmaf(vh - va, r2w[tt * 16 + c16], d);
            }
        }
#pragma unroll
        for (int off = 32; off > 0; off >>= 1) d += __shfl_xor(d, off);
        if (lane == 0) out[b] = 0.5f + 0.5f * tanhf(d);
    }
}

extern "C" void kernel_launch(void* const* d_in, const int* in_sizes, int n_in,
                              void* d_out, int out_size, void* d_ws, size_t ws_size,
                              hipStream_t stream) {
    const float* A         = (const float*)d_in[0];
    const float* X         = (const float*)d_in[1];
    const int*   home_mask = (const int*)  d_in[2];
    const float* We1       = (const float*)d_in[3];
    const float* be1       = (const float*)d_in[4];
    const float* We2       = (const float*)d_in[5];
    const float* be2       = (const float*)d_in[6];
    const float* rgcn_w    = (const float*)d_in[7];
    const float* rgcn_root = (const float*)d_in[8];
    const float* rgcn_b    = (const float*)d_in[9];
    const float* l1w       = (const float*)d_in[10];
    const float* l1b       = (const float*)d_in[11];
    const float* l2w       = (const float*)d_in[12];
    const float* l2b       = (const float*)d_in[13];
    const float* ln_g      = (const float*)d_in[14];
    const float* ln_b      = (const float*)d_in[15];
    const float* p1w       = (const float*)d_in[16];
    const float* p1b       = (const float*)d_in[17];
    const float* p2w       = (const float*)d_in[18];
    const float* p2b       = (const float*)d_in[19];
    const float* r1w       = (const float*)d_in[20];
    const float* r1b       = (const float*)d_in[21];
    const float* r2w       = (const float*)d_in[22];

    short* ws = (short*)d_ws;

    prep_weights<<<776, 64, 0, stream>>>(We1, We2, rgcn_w, rgcn_root,
                                         l1w, l2w, p1w, p2w, r1w, ws);
    gcn_main<<<B_, 64, 0, stream>>>(A, X, home_mask, be1, be2, rgcn_b,
                                    l1b, l2b, ln_g, ln_b, p1b, p2b,
                                    r1b, r2w, ws, (float*)d_out);
}